// Round 15
// baseline (424.074 us; speedup 1.0000x reference)
//
#include <hip/hip_runtime.h>
#include <math.h>

#define NB 256
#define NT 128
#define NDW 300
#define NH 128
#define NTYPE 8
#define NLEVEL 13
#define NN (NB*NT)

#define NBK 104       // (height 0..12) x (type 0..7) node buckets
#define CBLOCKS 64
#define PBLOCKS 2048  // phase grid: 256 subs per type x 8 types

// ib layout (ints), at byte offset 32MB of d_ws
#define BC 0                    // [64][104] per-block counts
#define BB 6656                 // [64][104] per-block base offsets
#define OFF 13312               // [105] bucket starts
#define NODE_LIST 13440         // [NN] int2 {node, parent_global or -1} (2*NN ints)
#define CDESC 79104             // [NN] (clist_start<<8)|child_count
#define CLIST 111872            // [NN] children grouped by parent (deterministic)

typedef __attribute__((ext_vector_type(8))) short short8;
typedef __attribute__((ext_vector_type(4))) float f32x4;

__global__ __launch_bounds__(256) void count_kernel(const int* __restrict__ dep_type,
    const int* __restrict__ height, int* ib) {
  __shared__ int cnt[NBK];
  for (int u = threadIdx.x; u < NBK; u += 256) cnt[u] = 0;
  __syncthreads();
  for (int i = blockIdx.x*256 + threadIdx.x; i < NN; i += CBLOCKS*256)
    atomicAdd(&cnt[height[i]*NTYPE + dep_type[i]], 1);
  __syncthreads();
  for (int u = threadIdx.x; u < NBK; u += 256)
    ib[BC + blockIdx.x*NBK + u] = cnt[u];
}

__global__ __launch_bounds__(128) void scan_kernel(int* ib) {
  __shared__ int total[NBK], start[NBK];
  int u = threadIdx.x;
  if (u < NBK) {
    int acc = 0;
    for (int b = 0; b < CBLOCKS; b++) {
      ib[BB + b*NBK + u] = acc;
      acc += ib[BC + b*NBK + u];
    }
    total[u] = acc;
  }
  __syncthreads();
  if (u == 0) {
    int acc = 0;
    for (int e = 0; e < NBK; e++) { start[e] = acc; ib[OFF+e] = acc; acc += total[e]; }
    ib[OFF+NBK] = acc;
  }
  __syncthreads();
  if (u < NBK) {
    int s = start[u];
    for (int b = 0; b < CBLOCKS; b++) ib[BB + b*NBK + u] += s;
  }
}

__global__ __launch_bounds__(256) void scatter_kernel(const int* __restrict__ parent,
    const int* __restrict__ dep_type, const int* __restrict__ height, int* ib) {
  __shared__ int base[NBK];
  __shared__ int cnt[NBK];
  int2* nl = (int2*)&ib[NODE_LIST];
  for (int u = threadIdx.x; u < NBK; u += 256) {
    base[u] = ib[BB + blockIdx.x*NBK + u];
    cnt[u] = 0;
  }
  __syncthreads();
  for (int i = blockIdx.x*256 + threadIdx.x; i < NN; i += CBLOCKS*256) {
    int bk = height[i]*NTYPE + dep_type[i];
    int pos = atomicAdd(&cnt[bk], 1);
    int p = parent[i];
    int pg = p >= 0 ? (i & ~(NT-1)) + p : -1;
    nl[base[bk] + pos] = make_int2(i, pg);
  }
}

// Per-sentence CSR of children (parents are sentence-local). Deterministic:
// rank of child = #earlier siblings. No global atomics.  [R13-proven]
__global__ __launch_bounds__(128) void csr_kernel(const int* __restrict__ parent,
    int* ib) {
  __shared__ int par[128], startl[128], hist[128];
  int b = blockIdx.x, i = threadIdx.x;
  int p = parent[b*128 + i];              // -1 only for i==0
  par[i] = p; hist[i] = 0;
  __syncthreads();
  if (p >= 0) atomicAdd(&hist[p], 1);     // LDS atomic
  __syncthreads();
  if (i == 0) {
    int acc = 0;
    for (int u = 0; u < 128; u++) { startl[u] = acc; acc += hist[u]; }
  }
  __syncthreads();
  if (p >= 0) {
    int rank = 0;
    for (int j = 1; j < i; j++) rank += (par[j] == p);   // deterministic order
    ib[CLIST + b*128 + startl[p] + rank] = b*128 + i;
  }
  ib[CDESC + b*128 + i] = ((b*128 + startl[i]) << 8) | hist[i];
}

__device__ __forceinline__ unsigned int pack_bf16(float a, float b) {
  unsigned int ua = __float_as_uint(a); ua += 0x7fff + ((ua >> 16) & 1);
  unsigned int ub = __float_as_uint(b); ub += 0x7fff + ((ub >> 16) & 1);
  return (ua >> 16) | (ub & 0xffff0000u);
}

// fast tanh: 1 - 2*rcp(e^{2x}+1); exact at +/-inf, ~1e-6 abs error
__device__ __forceinline__ float ftanh(float x) {
  float e = __expf(2.0f * x);
  return 1.0f - 2.0f * __builtin_amdgcn_rcpf(e + 1.0f);
}

// Transposed-packed bf16 weights: bwT[mat][d4][row] = uint2 of 4 bf16 =
// W[mat][row][4*d4..4*d4+3]. mat 0 = W_hr, mat 1+t = W_rel[t]. Coalesced build.
__global__ __launch_bounds__(256) void wcvt_kernel(const float* __restrict__ Whr,
    const float* __restrict__ Wrel, uint2* __restrict__ bwT) {
  int flat = blockIdx.x*256 + threadIdx.x;     // 0 .. 9*4096-1
  int mat = flat >> 12, rem = flat & 4095;
  int d4 = rem >> 7, row = rem & 127;
  const float* src = (mat == 0) ? &Whr[row*NH + d4*4]
                                : &Wrel[(size_t)(mat-1)*NH*NH + row*NH + d4*4];
  float4 v = *(const float4*)src;
  uint2 u; u.x = pack_bf16(v.x, v.y); u.y = pack_bf16(v.z, v.w);
  bwT[flat] = u;
}

// wx = token_emb @ W_wh.T via MFMA bf16. Tile 64m x 128n, K chunks of 32 (300 pad 320).
__global__ __launch_bounds__(256) void wx_kernel(const float* __restrict__ x,
    const float* __restrict__ Wwh, float* __restrict__ wx) {
  __shared__ __align__(16) unsigned int sA[64*16];    // [row][16 uints] = 32 bf16/row
  __shared__ __align__(16) unsigned int sB[128*16];
  int tid = threadIdx.x;
  int wave = tid >> 6, lane = tid & 63;
  size_t rowbase = (size_t)blockIdx.x * 64;
  f32x4 acc[8];
  #pragma unroll
  for (int ni = 0; ni < 8; ni++) acc[ni] = (f32x4){0.f,0.f,0.f,0.f};
  for (int kc = 0; kc < 320; kc += 32) {
    __syncthreads();
    #pragma unroll
    for (int q = 0; q < 2; q++) {             // stage A: 64 rows x 8 float4
      int flat = tid + q*256; int r = flat >> 3, f4 = flat & 7;
      int k0 = kc + f4*4;
      float4 v = make_float4(0.f,0.f,0.f,0.f);
      if (k0 + 3 < NDW) v = *(const float4*)&x[(rowbase + r)*NDW + k0];
      uint2 u; u.x = pack_bf16(v.x, v.y); u.y = pack_bf16(v.z, v.w);
      *(uint2*)&sA[r*16 + f4*2] = u;
    }
    #pragma unroll
    for (int q = 0; q < 4; q++) {             // stage B: 128 rows x 8 float4
      int flat = tid + q*256; int r = flat >> 3, f4 = flat & 7;
      int k0 = kc + f4*4;
      float4 v = make_float4(0.f,0.f,0.f,0.f);
      if (k0 + 3 < NDW) v = *(const float4*)&Wwh[(size_t)r*NDW + k0];
      uint2 u; u.x = pack_bf16(v.x, v.y); u.y = pack_bf16(v.z, v.w);
      *(uint2*)&sB[r*16 + f4*2] = u;
    }
    __syncthreads();
    short8 a = *(const short8*)&sA[(wave*16 + (lane & 15))*16 + (lane >> 4)*4];
    #pragma unroll
    for (int ni = 0; ni < 8; ni++) {
      short8 b = *(const short8*)&sB[(ni*16 + (lane & 15))*16 + (lane >> 4)*4];
      acc[ni] = __builtin_amdgcn_mfma_f32_16x16x32_bf16(a, b, acc[ni], 0, 0, 0);
    }
  }
  int rbase = wave*16 + (lane >> 4)*4;
  #pragma unroll
  for (int ni = 0; ni < 8; ni++)
    #pragma unroll
    for (int reg = 0; reg < 4; reg++)
      wx[(rowbase + rbase + reg)*NH + ni*16 + (lane & 15)] = acc[ni][reg];
}

// 4-node batched matvec, float2 lane mapping: lane owns output rows 2l,2l+1.
// One uint4 load per d4 serves both rows (adjacent in transposed table).
__device__ __forceinline__ void matvec4_T2(const uint2* __restrict__ wt,
    int lane, const float (*sv)[NH], float* o0, float* o1) {
  #pragma unroll
  for (int j = 0; j < 4; j++) { o0[j] = 0.f; o1[j] = 0.f; }
  #pragma unroll 4
  for (int d4 = 0; d4 < 32; d4++) {
    uint4 u = *(const uint4*)&wt[d4*128 + 2*lane];   // rows 2l (x,y), 2l+1 (z,w)
    float w00 = __uint_as_float(u.x << 16), w01 = __uint_as_float(u.x & 0xffff0000u);
    float w02 = __uint_as_float(u.y << 16), w03 = __uint_as_float(u.y & 0xffff0000u);
    float w10 = __uint_as_float(u.z << 16), w11 = __uint_as_float(u.z & 0xffff0000u);
    float w12 = __uint_as_float(u.w << 16), w13 = __uint_as_float(u.w & 0xffff0000u);
    #pragma unroll
    for (int j = 0; j < 4; j++) {
      float4 v = *(const float4*)&sv[j][d4*4];    // wave-uniform: LDS broadcast
      o0[j] += w00*v.x + w01*v.y + w02*v.z + w03*v.w;
      o1[j] += w10*v.x + w11*v.y + w12*v.z + w13*v.w;
    }
  }
}

// Phase k: nodes with height==k, bucketed by dep_type t=blockIdx&7:
//   seg_i = sum over children c of einfl[c]     (CSR pull-gather; NO atomics)
//   h_i = tanh(seg_i + simple_i)  (simple at k==0)  -> hbuf row i (write-once)
//   g = W_hr.h ; r = tanh(g + wx_parent); einfl[i] = W_rel[t].r  (plain store)
__global__ __launch_bounds__(256, 8) void phase_kernel(
    const uint2* __restrict__ bwT, const float* __restrict__ bwh,
    const float* __restrict__ wx, const int* __restrict__ ib,
    float* __restrict__ hbuf, float* __restrict__ einfl, int k) {
  int t = blockIdx.x & 7, sub = blockIdx.x >> 3;     // 256 subs per type
  int bs = ib[OFF + k*NTYPE + t];
  int be = ib[OFF + k*NTYPE + t + 1];
  int nbat = (be - bs + 3) >> 2;
  if (sub*4 >= nbat) return;                         // uniform early-exit
  __shared__ __align__(16) float sh[4][4][NH];       // 8 KB
  const int2* nl = (const int2*)&ib[NODE_LIST];
  int wave = threadIdx.x >> 6, lane = threadIdx.x & 63;
  int e0 = 2*lane;                                   // lane owns elements e0, e0+1
  const uint2* whr_t  = bwT;                         // mat 0
  const uint2* wrel_t = bwT + (size_t)(1 + t)*4096;  // mat 1+t
  float2 bv = *(const float2*)&bwh[e0];
  for (int b = sub*4 + wave; b < nbat; b += 256*4) {
    int base = bs + b*4;
    int cnt = be - base; if (cnt > 4) cnt = 4;
    int2 np[4];
    // pass 1: node records (node idx + precomputed global parent)
    #pragma unroll
    for (int j = 0; j < 4; j++) {
      int it = base + j; if (it >= be) it = be - 1;  // clamp tail (wave-uniform)
      np[j] = nl[it];
    }
    // pass 2: own wx + parent wx rows, back-to-back
    float2 wxv[4], pw[4];
    #pragma unroll
    for (int j = 0; j < 4; j++)
      wxv[j] = *(const float2*)&wx[(size_t)np[j].x*NH + e0];
    #pragma unroll
    for (int j = 0; j < 4; j++) {
      int p = np[j].y >= 0 ? np[j].y : np[j].x;
      pw[j] = *(const float2*)&wx[(size_t)p*NH + e0];
    }
    // seg via CSR pull-gather (k>0); wave-uniform child loop per j
    float2 seg[4];
    #pragma unroll
    for (int j = 0; j < 4; j++) seg[j] = make_float2(0.f, 0.f);
    if (k > 0) {
      int cd[4];
      #pragma unroll
      for (int j = 0; j < 4; j++) cd[j] = ib[CDESC + np[j].x];
      #pragma unroll
      for (int j = 0; j < 4; j++) {
        int cs = cd[j] >> 8, cc = cd[j] & 255;
        for (int ci = 0; ci < cc; ci++) {
          int c = ib[CLIST + cs + ci];
          float2 v = *(const float2*)&einfl[(size_t)c*NH + e0];
          seg[j].x += v.x; seg[j].y += v.y;
        }
      }
    }
    // finalize h, publish to LDS + hbuf (write-once)
    #pragma unroll
    for (int j = 0; j < 4; j++) {
      float s0 = ftanh(wxv[j].x + bv.x);
      float s1 = ftanh(wxv[j].y + bv.y);
      float h0, h1;
      if (k == 0) { h0 = s0; h1 = s1; }
      else { h0 = ftanh(seg[j].x + s0); h1 = ftanh(seg[j].y + s1); }
      if (j < cnt)
        *(float2*)&hbuf[(size_t)np[j].x*NH + e0] = make_float2(h0, h1);  // final h
      *(float2*)&sh[wave][j][e0] = make_float2(h0, h1);   // wave-synchronous LDS
    }
    float g0[4], g1[4];
    matvec4_T2(whr_t, lane, sh[wave], g0, g1);       // g = W_hr . h
    #pragma unroll
    for (int j = 0; j < 4; j++) {                    // r = tanh(g + wx_parent)
      float r0 = ftanh(g0[j] + pw[j].x);
      float r1 = ftanh(g1[j] + pw[j].y);
      *(float2*)&sh[wave][j][e0] = make_float2(r0, r1);
    }
    float o0[4], o1[4];
    matvec4_T2(wrel_t, lane, sh[wave], o0, o1);      // infl = W_rel[t] . r
    #pragma unroll
    for (int j = 0; j < 4; j++) if (j < cnt && np[j].y >= 0)
      *(float2*)&einfl[(size_t)np[j].x*NH + e0] = make_float2(o0[j], o1[j]);
  }
}

extern "C" void kernel_launch(void* const* d_in, const int* in_sizes, int n_in,
                              void* d_out, int out_size, void* d_ws, size_t ws_size,
                              hipStream_t stream) {
  const float* token  = (const float*)d_in[0];
  const float* Wwh    = (const float*)d_in[1];
  const float* bwh    = (const float*)d_in[2];
  const float* Whr    = (const float*)d_in[3];
  const float* Wrel   = (const float*)d_in[4];
  const int*   parent = (const int*)d_in[5];
  const int*   dep    = (const int*)d_in[6];
  const int*   height = (const int*)d_in[7];

  float* hbuf  = (float*)d_out;                         // final h (write-once)
  float* wx    = (float*)d_ws;                          // [NN,NH] f32, 16MB
  float* einfl = (float*)((char*)d_ws + 16777216);      // [NN,NH] f32, 16MB
  int*   ib    = (int*)((char*)d_ws + 33554432);        // sort + CSR (~565KB)
  uint2* bwT   = (uint2*)((char*)d_ws + 33554432 + 655360); // 288KB bf16 weights

  wcvt_kernel<<<144, 256, 0, stream>>>(Whr, Wrel, bwT);
  count_kernel<<<CBLOCKS, 256, 0, stream>>>(dep, height, ib);
  scan_kernel<<<1, 128, 0, stream>>>(ib);
  scatter_kernel<<<CBLOCKS, 256, 0, stream>>>(parent, dep, height, ib);
  csr_kernel<<<NB, 128, 0, stream>>>(parent, ib);
  wx_kernel<<<NN/64, 256, 0, stream>>>(token, Wwh, wx);
  for (int k = 0; k < NLEVEL; k++)
    phase_kernel<<<PBLOCKS, 256, 0, stream>>>(bwT, bwh, wx, ib, hbuf, einfl, k);
}

// Round 16
// 313.818 us; speedup vs baseline: 1.3513x; 1.3513x over previous
//
#include <hip/hip_runtime.h>
#include <math.h>

#define NB 256
#define NT 128
#define NDW 300
#define NH 128
#define NTYPE 8
#define NLEVEL 13
#define NN (NB*NT)

typedef __attribute__((ext_vector_type(8))) short short8;
typedef __attribute__((ext_vector_type(4))) float f32x4;

__device__ __forceinline__ unsigned int pack_bf16(float a, float b) {
  unsigned int ua = __float_as_uint(a); ua += 0x7fff + ((ua >> 16) & 1);
  unsigned int ub = __float_as_uint(b); ub += 0x7fff + ((ub >> 16) & 1);
  return (ua >> 16) | (ub & 0xffff0000u);
}

// fast tanh: 1 - 2*rcp(e^{2x}+1); exact at +/-inf, ~1e-6 abs error
__device__ __forceinline__ float ftanh(float x) {
  float e = __expf(2.0f * x);
  return 1.0f - 2.0f * __builtin_amdgcn_rcpf(e + 1.0f);
}

// Transposed-packed bf16 weights: bwT[mat][d4][row] = uint2 of 4 bf16 =
// W[mat][row][4*d4..4*d4+3]. mat 0 = W_hr, mat 1+t = W_rel[t]. Coalesced build.
__global__ __launch_bounds__(256) void wcvt_kernel(const float* __restrict__ Whr,
    const float* __restrict__ Wrel, uint2* __restrict__ bwT) {
  int flat = blockIdx.x*256 + threadIdx.x;     // 0 .. 9*4096-1
  int mat = flat >> 12, rem = flat & 4095;
  int d4 = rem >> 7, row = rem & 127;
  const float* src = (mat == 0) ? &Whr[row*NH + d4*4]
                                : &Wrel[(size_t)(mat-1)*NH*NH + row*NH + d4*4];
  float4 v = *(const float4*)src;
  uint2 u; u.x = pack_bf16(v.x, v.y); u.y = pack_bf16(v.z, v.w);
  bwT[flat] = u;
}

// wx = token_emb @ W_wh.T via MFMA bf16. Tile 64m x 128n, K chunks of 32 (300 pad 320).
__global__ __launch_bounds__(256) void wx_kernel(const float* __restrict__ x,
    const float* __restrict__ Wwh, float* __restrict__ wx) {
  __shared__ __align__(16) unsigned int sA[64*16];    // [row][16 uints] = 32 bf16/row
  __shared__ __align__(16) unsigned int sB[128*16];
  int tid = threadIdx.x;
  int wave = tid >> 6, lane = tid & 63;
  size_t rowbase = (size_t)blockIdx.x * 64;
  f32x4 acc[8];
  #pragma unroll
  for (int ni = 0; ni < 8; ni++) acc[ni] = (f32x4){0.f,0.f,0.f,0.f};
  for (int kc = 0; kc < 320; kc += 32) {
    __syncthreads();
    #pragma unroll
    for (int q = 0; q < 2; q++) {             // stage A: 64 rows x 8 float4
      int flat = tid + q*256; int r = flat >> 3, f4 = flat & 7;
      int k0 = kc + f4*4;
      float4 v = make_float4(0.f,0.f,0.f,0.f);
      if (k0 + 3 < NDW) v = *(const float4*)&x[(rowbase + r)*NDW + k0];
      uint2 u; u.x = pack_bf16(v.x, v.y); u.y = pack_bf16(v.z, v.w);
      *(uint2*)&sA[r*16 + f4*2] = u;
    }
    #pragma unroll
    for (int q = 0; q < 4; q++) {             // stage B: 128 rows x 8 float4
      int flat = tid + q*256; int r = flat >> 3, f4 = flat & 7;
      int k0 = kc + f4*4;
      float4 v = make_float4(0.f,0.f,0.f,0.f);
      if (k0 + 3 < NDW) v = *(const float4*)&Wwh[(size_t)r*NDW + k0];
      uint2 u; u.x = pack_bf16(v.x, v.y); u.y = pack_bf16(v.z, v.w);
      *(uint2*)&sB[r*16 + f4*2] = u;
    }
    __syncthreads();
    short8 a = *(const short8*)&sA[(wave*16 + (lane & 15))*16 + (lane >> 4)*4];
    #pragma unroll
    for (int ni = 0; ni < 8; ni++) {
      short8 b = *(const short8*)&sB[(ni*16 + (lane & 15))*16 + (lane >> 4)*4];
      acc[ni] = __builtin_amdgcn_mfma_f32_16x16x32_bf16(a, b, acc[ni], 0, 0, 0);
    }
  }
  int rbase = wave*16 + (lane >> 4)*4;
  #pragma unroll
  for (int ni = 0; ni < 8; ni++)
    #pragma unroll
    for (int reg = 0; reg < 4; reg++)
      wx[(rowbase + rbase + reg)*NH + ni*16 + (lane & 15)] = acc[ni][reg];
}

// 4-node batched matvec, float2 lane mapping: lane owns output rows 2l,2l+1.
// One uint4 load per d4 serves both rows (adjacent in transposed table). [R10-proven]
__device__ __forceinline__ void matvec4_T2(const uint2* __restrict__ wt,
    int lane, const float (*sv)[NH], float* o0, float* o1) {
  #pragma unroll
  for (int j = 0; j < 4; j++) { o0[j] = 0.f; o1[j] = 0.f; }
  #pragma unroll 4
  for (int d4 = 0; d4 < 32; d4++) {
    uint4 u = *(const uint4*)&wt[d4*128 + 2*lane];   // rows 2l (x,y), 2l+1 (z,w)
    float w00 = __uint_as_float(u.x << 16), w01 = __uint_as_float(u.x & 0xffff0000u);
    float w02 = __uint_as_float(u.y << 16), w03 = __uint_as_float(u.y & 0xffff0000u);
    float w10 = __uint_as_float(u.z << 16), w11 = __uint_as_float(u.z & 0xffff0000u);
    float w12 = __uint_as_float(u.w << 16), w13 = __uint_as_float(u.w & 0xffff0000u);
    #pragma unroll
    for (int j = 0; j < 4; j++) {
      float4 v = *(const float4*)&sv[j][d4*4];    // wave-uniform: LDS broadcast
      o0[j] += w00*v.x + w01*v.y + w02*v.z + w03*v.w;
      o1[j] += w10*v.x + w11*v.y + w12*v.z + w13*v.w;
    }
  }
}

// One block per sentence. 1024 threads = 16 waves; wave w serves type t=w&7,
// sub s=w>>3 (2 waves per type). All 13 levels inside the block, synced by
// __syncthreads. seg accumulates in LDS (in-CU atomics). hbuf written once/node.
__global__ __launch_bounds__(1024) void tree_kernel(
    const uint2* __restrict__ bwT, const float* __restrict__ bwh,
    const float* __restrict__ wx, const int* __restrict__ parent,
    const int* __restrict__ dep_type, const int* __restrict__ height,
    float* __restrict__ hbuf) {
  __shared__ float sseg[NT][NH];                  // 64 KB seg accumulators
  __shared__ __align__(16) float sh[16][4][NH];   // 32 KB per-wave batch vectors
  __shared__ int sord[NT], par_l[NT];
  __shared__ int gs[105], fill[104], hist[104];
  int b = blockIdx.x, tid = threadIdx.x;
  int wave = tid >> 6, lane = tid & 63;
  int e0 = 2*lane;
  // zero sseg
  for (int idx = tid; idx < NT*NH/4; idx += 1024)
    ((float4*)sseg)[idx] = make_float4(0.f,0.f,0.f,0.f);
  if (tid < 104) hist[tid] = 0;
  __syncthreads();
  int mykey = 0;
  if (tid < NT) {
    int g = b*NT + tid;
    mykey = height[g]*NTYPE + dep_type[g];
    par_l[tid] = parent[g];
    atomicAdd(&hist[mykey], 1);                   // LDS atomic
  }
  __syncthreads();
  if (tid == 0) {
    int acc = 0;
    for (int u = 0; u < 104; u++) { gs[u] = acc; acc += hist[u]; }
    gs[104] = acc;
  }
  __syncthreads();
  if (tid < 104) fill[tid] = gs[tid];
  __syncthreads();
  if (tid < NT) {
    int pos = atomicAdd(&fill[mykey], 1);         // LDS atomic
    sord[pos] = tid;
  }
  int t = wave & 7, s = wave >> 3;
  const uint2* whr_t  = bwT;                      // mat 0
  const uint2* wrel_t = bwT + (size_t)(1 + t)*4096;
  float2 bv = *(const float2*)&bwh[e0];
  const float* wxb = wx + (size_t)b*NT*NH;
  float* hb = hbuf + (size_t)b*NT*NH;
  __syncthreads();
  for (int k = 0; k < NLEVEL; k++) {
    int q0 = gs[k*NTYPE + t], q1 = gs[k*NTYPE + t + 1];
    for (int base = q0 + s*4; base < q1; base += 8) {
      int cnt = q1 - base; if (cnt > 4) cnt = 4;
      int nl[4], pl[4];
      #pragma unroll
      for (int j = 0; j < 4; j++) {
        int it = base + j; if (it >= q1) it = q1 - 1;   // clamp tail
        nl[j] = sord[it];
        pl[j] = par_l[nl[j]];
      }
      float2 wxv[4], pw[4], sg[4];
      #pragma unroll
      for (int j = 0; j < 4; j++)
        wxv[j] = *(const float2*)&wxb[(size_t)nl[j]*NH + e0];
      #pragma unroll
      for (int j = 0; j < 4; j++) {
        int p = pl[j] >= 0 ? pl[j] : nl[j];
        pw[j] = *(const float2*)&wxb[(size_t)p*NH + e0];
      }
      #pragma unroll
      for (int j = 0; j < 4; j++)
        sg[j] = *(const float2*)&sseg[nl[j]][e0];
      // finalize h (leaf at k==0: h = simple, NOT tanh(0+simple))
      #pragma unroll
      for (int j = 0; j < 4; j++) {
        float s0 = ftanh(wxv[j].x + bv.x);
        float s1 = ftanh(wxv[j].y + bv.y);
        float h0, h1;
        if (k == 0) { h0 = s0; h1 = s1; }
        else { h0 = ftanh(sg[j].x + s0); h1 = ftanh(sg[j].y + s1); }
        if (j < cnt)
          *(float2*)&hb[(size_t)nl[j]*NH + e0] = make_float2(h0, h1);  // final h
        *(float2*)&sh[wave][j][e0] = make_float2(h0, h1);  // wave-synchronous LDS
      }
      float g0v[4], g1v[4];
      matvec4_T2(whr_t, lane, sh[wave], g0v, g1v);  // g = W_hr . h
      #pragma unroll
      for (int j = 0; j < 4; j++) {                 // r = tanh(g + wx_parent)
        float r0 = ftanh(g0v[j] + pw[j].x);
        float r1 = ftanh(g1v[j] + pw[j].y);
        *(float2*)&sh[wave][j][e0] = make_float2(r0, r1);
      }
      float o0[4], o1[4];
      matvec4_T2(wrel_t, lane, sh[wave], o0, o1);   // infl = W_rel[t] . r
      #pragma unroll
      for (int j = 0; j < 4; j++) if (j < cnt && pl[j] >= 0) {
        atomicAdd(&sseg[pl[j]][e0],     o0[j]);     // LDS atomic (in-CU)
        atomicAdd(&sseg[pl[j]][e0 + 1], o1[j]);
      }
    }
    __syncthreads();                                // level boundary (block-local)
  }
}

extern "C" void kernel_launch(void* const* d_in, const int* in_sizes, int n_in,
                              void* d_out, int out_size, void* d_ws, size_t ws_size,
                              hipStream_t stream) {
  const float* token  = (const float*)d_in[0];
  const float* Wwh    = (const float*)d_in[1];
  const float* bwh    = (const float*)d_in[2];
  const float* Whr    = (const float*)d_in[3];
  const float* Wrel   = (const float*)d_in[4];
  const int*   parent = (const int*)d_in[5];
  const int*   dep    = (const int*)d_in[6];
  const int*   height = (const int*)d_in[7];

  float* hbuf = (float*)d_out;                          // final h (write-once)
  float* wx   = (float*)d_ws;                           // [NN,NH] f32, 16MB
  uint2* bwT  = (uint2*)((char*)d_ws + 16777216);       // 288KB bf16 weights

  wcvt_kernel<<<144, 256, 0, stream>>>(Whr, Wrel, bwT);
  wx_kernel<<<NN/64, 256, 0, stream>>>(token, Wwh, wx);
  tree_kernel<<<NB, 1024, 0, stream>>>(bwT, bwh, wx, parent, dep, height, hbuf);
}

// Round 17
// 292.794 us; speedup vs baseline: 1.4484x; 1.0718x over previous
//
#include <hip/hip_runtime.h>
#include <math.h>

#define NB 256
#define NT 128
#define NDW 300
#define NH 128
#define NTYPE 8
#define NLEVEL 13
#define NN (NB*NT)

typedef __attribute__((ext_vector_type(8))) short short8;
typedef __attribute__((ext_vector_type(4))) float f32x4;

__device__ __forceinline__ unsigned int pack_bf16(float a, float b) {
  unsigned int ua = __float_as_uint(a); ua += 0x7fff + ((ua >> 16) & 1);
  unsigned int ub = __float_as_uint(b); ub += 0x7fff + ((ub >> 16) & 1);
  return (ua >> 16) | (ub & 0xffff0000u);
}

// fast tanh: 1 - 2*rcp(e^{2x}+1); exact at +/-inf, ~1e-6 abs error
__device__ __forceinline__ float ftanh(float x) {
  float e = __expf(2.0f * x);
  return 1.0f - 2.0f * __builtin_amdgcn_rcpf(e + 1.0f);
}

// Transposed-packed bf16 weights: bwT[mat][d4][row] = uint2 of 4 bf16 =
// W[mat][row][4*d4..4*d4+3]. mat 0 = W_hr, mat 1+t = W_rel[t]. Coalesced build.
__global__ __launch_bounds__(256) void wcvt_kernel(const float* __restrict__ Whr,
    const float* __restrict__ Wrel, uint2* __restrict__ bwT) {
  int flat = blockIdx.x*256 + threadIdx.x;     // 0 .. 9*4096-1
  int mat = flat >> 12, rem = flat & 4095;
  int d4 = rem >> 7, row = rem & 127;
  const float* src = (mat == 0) ? &Whr[row*NH + d4*4]
                                : &Wrel[(size_t)(mat-1)*NH*NH + row*NH + d4*4];
  float4 v = *(const float4*)src;
  uint2 u; u.x = pack_bf16(v.x, v.y); u.y = pack_bf16(v.z, v.w);
  bwT[flat] = u;
}

// wx = token_emb @ W_wh.T via MFMA bf16. Tile 64m x 128n, K chunks of 32 (300 pad 320).
__global__ __launch_bounds__(256) void wx_kernel(const float* __restrict__ x,
    const float* __restrict__ Wwh, float* __restrict__ wx) {
  __shared__ __align__(16) unsigned int sA[64*16];    // [row][16 uints] = 32 bf16/row
  __shared__ __align__(16) unsigned int sB[128*16];
  int tid = threadIdx.x;
  int wave = tid >> 6, lane = tid & 63;
  size_t rowbase = (size_t)blockIdx.x * 64;
  f32x4 acc[8];
  #pragma unroll
  for (int ni = 0; ni < 8; ni++) acc[ni] = (f32x4){0.f,0.f,0.f,0.f};
  for (int kc = 0; kc < 320; kc += 32) {
    __syncthreads();
    #pragma unroll
    for (int q = 0; q < 2; q++) {             // stage A: 64 rows x 8 float4
      int flat = tid + q*256; int r = flat >> 3, f4 = flat & 7;
      int k0 = kc + f4*4;
      float4 v = make_float4(0.f,0.f,0.f,0.f);
      if (k0 + 3 < NDW) v = *(const float4*)&x[(rowbase + r)*NDW + k0];
      uint2 u; u.x = pack_bf16(v.x, v.y); u.y = pack_bf16(v.z, v.w);
      *(uint2*)&sA[r*16 + f4*2] = u;
    }
    #pragma unroll
    for (int q = 0; q < 4; q++) {             // stage B: 128 rows x 8 float4
      int flat = tid + q*256; int r = flat >> 3, f4 = flat & 7;
      int k0 = kc + f4*4;
      float4 v = make_float4(0.f,0.f,0.f,0.f);
      if (k0 + 3 < NDW) v = *(const float4*)&Wwh[(size_t)r*NDW + k0];
      uint2 u; u.x = pack_bf16(v.x, v.y); u.y = pack_bf16(v.z, v.w);
      *(uint2*)&sB[r*16 + f4*2] = u;
    }
    __syncthreads();
    short8 a = *(const short8*)&sA[(wave*16 + (lane & 15))*16 + (lane >> 4)*4];
    #pragma unroll
    for (int ni = 0; ni < 8; ni++) {
      short8 b = *(const short8*)&sB[(ni*16 + (lane & 15))*16 + (lane >> 4)*4];
      acc[ni] = __builtin_amdgcn_mfma_f32_16x16x32_bf16(a, b, acc[ni], 0, 0, 0);
    }
  }
  int rbase = wave*16 + (lane >> 4)*4;
  #pragma unroll
  for (int ni = 0; ni < 8; ni++)
    #pragma unroll
    for (int reg = 0; reg < 4; reg++)
      wx[(rowbase + rbase + reg)*NH + ni*16 + (lane & 15)] = acc[ni][reg];
}

// 4-node batched matvec, float2 lane mapping: lane owns output rows 2l,2l+1.
// Single weight stream (all 4 nodes same type). [R10-proven]
__device__ __forceinline__ void matvec4_T2(const uint2* __restrict__ wt,
    int lane, const float (*sv)[NH], float* o0, float* o1) {
  #pragma unroll
  for (int j = 0; j < 4; j++) { o0[j] = 0.f; o1[j] = 0.f; }
  #pragma unroll 4
  for (int d4 = 0; d4 < 32; d4++) {
    uint4 u = *(const uint4*)&wt[d4*128 + 2*lane];   // rows 2l (x,y), 2l+1 (z,w)
    float w00 = __uint_as_float(u.x << 16), w01 = __uint_as_float(u.x & 0xffff0000u);
    float w02 = __uint_as_float(u.y << 16), w03 = __uint_as_float(u.y & 0xffff0000u);
    float w10 = __uint_as_float(u.z << 16), w11 = __uint_as_float(u.z & 0xffff0000u);
    float w12 = __uint_as_float(u.w << 16), w13 = __uint_as_float(u.w & 0xffff0000u);
    #pragma unroll
    for (int j = 0; j < 4; j++) {
      float4 v = *(const float4*)&sv[j][d4*4];    // wave-uniform: LDS broadcast
      o0[j] += w00*v.x + w01*v.y + w02*v.z + w03*v.w;
      o1[j] += w10*v.x + w11*v.y + w12*v.z + w13*v.w;
    }
  }
}

// Mixed-type variant: per-node weight pointer (duplicate rows hit L1).
__device__ __forceinline__ void matvec4_mixed(const uint2* __restrict__ bwT,
    const int* tj, int lane, const float (*sv)[NH], float* o0, float* o1) {
  const uint2* wt0 = bwT + (size_t)(1 + tj[0])*4096;
  const uint2* wt1 = bwT + (size_t)(1 + tj[1])*4096;
  const uint2* wt2 = bwT + (size_t)(1 + tj[2])*4096;
  const uint2* wt3 = bwT + (size_t)(1 + tj[3])*4096;
  #pragma unroll
  for (int j = 0; j < 4; j++) { o0[j] = 0.f; o1[j] = 0.f; }
  #pragma unroll 2
  for (int d4 = 0; d4 < 32; d4++) {
    int off = d4*128 + 2*lane;
    uint4 u0 = *(const uint4*)&wt0[off];
    uint4 u1 = *(const uint4*)&wt1[off];
    uint4 u2 = *(const uint4*)&wt2[off];
    uint4 u3 = *(const uint4*)&wt3[off];
    const uint4 uu[4] = {u0, u1, u2, u3};
    #pragma unroll
    for (int j = 0; j < 4; j++) {
      float4 v = *(const float4*)&sv[j][d4*4];
      float w00 = __uint_as_float(uu[j].x << 16), w01 = __uint_as_float(uu[j].x & 0xffff0000u);
      float w02 = __uint_as_float(uu[j].y << 16), w03 = __uint_as_float(uu[j].y & 0xffff0000u);
      float w10 = __uint_as_float(uu[j].z << 16), w11 = __uint_as_float(uu[j].z & 0xffff0000u);
      float w12 = __uint_as_float(uu[j].w << 16), w13 = __uint_as_float(uu[j].w & 0xffff0000u);
      o0[j] += w00*v.x + w01*v.y + w02*v.z + w03*v.w;
      o1[j] += w10*v.x + w11*v.y + w12*v.z + w13*v.w;
    }
  }
}

// One block per sentence, 1024 threads = 16 waves. All 13 levels in-block.
// Per level: nodes sorted by type (sord); batches of 4 consecutive nodes form a
// POOL shared by all 16 waves (bi = wave, wave+16, ...). Type-pure batches take
// the single-stream matvec; mixed take per-node streams. seg accumulates in LDS.
__global__ __launch_bounds__(1024) void tree_kernel(
    const uint2* __restrict__ bwT, const float* __restrict__ bwh,
    const float* __restrict__ wx, const int* __restrict__ parent,
    const int* __restrict__ dep_type, const int* __restrict__ height,
    float* __restrict__ hbuf) {
  __shared__ float sseg[NT][NH];                  // 64 KB seg accumulators
  __shared__ __align__(16) float sh[16][4][NH];   // 32 KB per-wave batch vectors
  __shared__ int sord[NT], par_l[NT], typ_l[NT];
  __shared__ int gs[105], fill[104], hist[104];
  int b = blockIdx.x, tid = threadIdx.x;
  int wave = tid >> 6, lane = tid & 63;
  int e0 = 2*lane;
  for (int idx = tid; idx < NT*NH/4; idx += 1024)
    ((float4*)sseg)[idx] = make_float4(0.f,0.f,0.f,0.f);
  if (tid < 104) hist[tid] = 0;
  __syncthreads();
  int mykey = 0;
  if (tid < NT) {
    int g = b*NT + tid;
    int ty = dep_type[g];
    typ_l[tid] = ty;
    mykey = height[g]*NTYPE + ty;
    par_l[tid] = parent[g];
    atomicAdd(&hist[mykey], 1);                   // LDS atomic
  }
  __syncthreads();
  if (tid == 0) {
    int acc = 0;
    for (int u = 0; u < 104; u++) { gs[u] = acc; acc += hist[u]; }
    gs[104] = acc;
  }
  __syncthreads();
  if (tid < 104) fill[tid] = gs[tid];
  __syncthreads();
  if (tid < NT) {
    int pos = atomicAdd(&fill[mykey], 1);         // LDS atomic
    sord[pos] = tid;
  }
  const float* wxb = wx + (size_t)b*NT*NH;
  float* hb = hbuf + (size_t)b*NT*NH;
  float2 bv = *(const float2*)&bwh[e0];
  __syncthreads();
  for (int k = 0; k < NLEVEL; k++) {
    int ls = gs[k*NTYPE], le = gs[k*NTYPE + NTYPE];
    int nbat = (le - ls + 3) >> 2;
    for (int bi = wave; bi < nbat; bi += 16) {    // dynamic pool over all waves
      int base = ls + bi*4;
      int cnt = le - base; if (cnt > 4) cnt = 4;
      int nl[4], pl[4], tj[4];
      #pragma unroll
      for (int j = 0; j < 4; j++) {
        int it = base + j; if (it >= le) it = le - 1;   // clamp tail
        nl[j] = sord[it];
        pl[j] = par_l[nl[j]];
        tj[j] = typ_l[nl[j]];
      }
      float2 wxv[4], pw[4], sg[4];
      #pragma unroll
      for (int j = 0; j < 4; j++)
        wxv[j] = *(const float2*)&wxb[(size_t)nl[j]*NH + e0];
      #pragma unroll
      for (int j = 0; j < 4; j++) {
        int p = pl[j] >= 0 ? pl[j] : nl[j];
        pw[j] = *(const float2*)&wxb[(size_t)p*NH + e0];
      }
      #pragma unroll
      for (int j = 0; j < 4; j++)
        sg[j] = *(const float2*)&sseg[nl[j]][e0];
      // finalize h
      #pragma unroll
      for (int j = 0; j < 4; j++) {
        float s0 = ftanh(wxv[j].x + bv.x);
        float s1 = ftanh(wxv[j].y + bv.y);
        float h0, h1;
        if (k == 0) { h0 = s0; h1 = s1; }
        else { h0 = ftanh(sg[j].x + s0); h1 = ftanh(sg[j].y + s1); }
        if (j < cnt)
          *(float2*)&hb[(size_t)nl[j]*NH + e0] = make_float2(h0, h1);  // final h
        *(float2*)&sh[wave][j][e0] = make_float2(h0, h1);  // wave-synchronous LDS
      }
      float g0v[4], g1v[4];
      matvec4_T2(bwT, lane, sh[wave], g0v, g1v);  // g = W_hr . h  (mat 0)
      #pragma unroll
      for (int j = 0; j < 4; j++) {               // r = tanh(g + wx_parent)
        float r0 = ftanh(g0v[j] + pw[j].x);
        float r1 = ftanh(g1v[j] + pw[j].y);
        *(float2*)&sh[wave][j][e0] = make_float2(r0, r1);
      }
      float o0[4], o1[4];
      if (tj[0] == tj[1] && tj[1] == tj[2] && tj[2] == tj[3])      // type-pure
        matvec4_T2(bwT + (size_t)(1 + tj[0])*4096, lane, sh[wave], o0, o1);
      else
        matvec4_mixed(bwT, tj, lane, sh[wave], o0, o1);
      #pragma unroll
      for (int j = 0; j < 4; j++) if (j < cnt && pl[j] >= 0) {
        atomicAdd(&sseg[pl[j]][e0],     o0[j]);   // LDS atomic (in-CU)
        atomicAdd(&sseg[pl[j]][e0 + 1], o1[j]);
      }
    }
    __syncthreads();                              // level boundary (block-local)
  }
}

extern "C" void kernel_launch(void* const* d_in, const int* in_sizes, int n_in,
                              void* d_out, int out_size, void* d_ws, size_t ws_size,
                              hipStream_t stream) {
  const float* token  = (const float*)d_in[0];
  const float* Wwh    = (const float*)d_in[1];
  const float* bwh    = (const float*)d_in[2];
  const float* Whr    = (const float*)d_in[3];
  const float* Wrel   = (const float*)d_in[4];
  const int*   parent = (const int*)d_in[5];
  const int*   dep    = (const int*)d_in[6];
  const int*   height = (const int*)d_in[7];

  float* hbuf = (float*)d_out;                          // final h (write-once)
  float* wx   = (float*)d_ws;                           // [NN,NH] f32, 16MB
  uint2* bwT  = (uint2*)((char*)d_ws + 16777216);       // 288KB bf16 weights

  wcvt_kernel<<<144, 256, 0, stream>>>(Whr, Wrel, bwT);
  wx_kernel<<<NN/64, 256, 0, stream>>>(token, Wwh, wx);
  tree_kernel<<<NB, 1024, 0, stream>>>(bwT, bwh, wx, parent, dep, height, hbuf);
}

// Round 18
// 286.261 us; speedup vs baseline: 1.4814x; 1.0228x over previous
//
#include <hip/hip_runtime.h>
#include <math.h>

#define NB 256
#define NT 128
#define NDW 300
#define NH 128
#define NTYPE 8
#define NLEVEL 13
#define NN (NB*NT)

typedef __attribute__((ext_vector_type(8))) short short8;
typedef __attribute__((ext_vector_type(4))) float f32x4;

__device__ __forceinline__ unsigned int pack_bf16(float a, float b) {
  unsigned int ua = __float_as_uint(a); ua += 0x7fff + ((ua >> 16) & 1);
  unsigned int ub = __float_as_uint(b); ub += 0x7fff + ((ub >> 16) & 1);
  return (ua >> 16) | (ub & 0xffff0000u);
}

// fast tanh: 1 - 2*rcp(e^{2x}+1); exact at +/-inf, ~1e-6 abs error
__device__ __forceinline__ float ftanh(float x) {
  float e = __expf(2.0f * x);
  return 1.0f - 2.0f * __builtin_amdgcn_rcpf(e + 1.0f);
}

// Transposed-packed bf16 weights: bwT[mat][d4][row] = uint2 of 4 bf16 =
// W[mat][row][4*d4..4*d4+3]. mat 0 = W_hr, mat 1+t = W_rel[t]. Coalesced build.
__global__ __launch_bounds__(256) void wcvt_kernel(const float* __restrict__ Whr,
    const float* __restrict__ Wrel, uint2* __restrict__ bwT) {
  int flat = blockIdx.x*256 + threadIdx.x;     // 0 .. 9*4096-1
  int mat = flat >> 12, rem = flat & 4095;
  int d4 = rem >> 7, row = rem & 127;
  const float* src = (mat == 0) ? &Whr[row*NH + d4*4]
                                : &Wrel[(size_t)(mat-1)*NH*NH + row*NH + d4*4];
  float4 v = *(const float4*)src;
  uint2 u; u.x = pack_bf16(v.x, v.y); u.y = pack_bf16(v.z, v.w);
  bwT[flat] = u;
}

// wx = token_emb @ W_wh.T via MFMA bf16. Tile 64m x 128n, K chunks of 32 (300 pad 320).
__global__ __launch_bounds__(256) void wx_kernel(const float* __restrict__ x,
    const float* __restrict__ Wwh, float* __restrict__ wx) {
  __shared__ __align__(16) unsigned int sA[64*16];    // [row][16 uints] = 32 bf16/row
  __shared__ __align__(16) unsigned int sB[128*16];
  int tid = threadIdx.x;
  int wave = tid >> 6, lane = tid & 63;
  size_t rowbase = (size_t)blockIdx.x * 64;
  f32x4 acc[8];
  #pragma unroll
  for (int ni = 0; ni < 8; ni++) acc[ni] = (f32x4){0.f,0.f,0.f,0.f};
  for (int kc = 0; kc < 320; kc += 32) {
    __syncthreads();
    #pragma unroll
    for (int q = 0; q < 2; q++) {             // stage A: 64 rows x 8 float4
      int flat = tid + q*256; int r = flat >> 3, f4 = flat & 7;
      int k0 = kc + f4*4;
      float4 v = make_float4(0.f,0.f,0.f,0.f);
      if (k0 + 3 < NDW) v = *(const float4*)&x[(rowbase + r)*NDW + k0];
      uint2 u; u.x = pack_bf16(v.x, v.y); u.y = pack_bf16(v.z, v.w);
      *(uint2*)&sA[r*16 + f4*2] = u;
    }
    #pragma unroll
    for (int q = 0; q < 4; q++) {             // stage B: 128 rows x 8 float4
      int flat = tid + q*256; int r = flat >> 3, f4 = flat & 7;
      int k0 = kc + f4*4;
      float4 v = make_float4(0.f,0.f,0.f,0.f);
      if (k0 + 3 < NDW) v = *(const float4*)&Wwh[(size_t)r*NDW + k0];
      uint2 u; u.x = pack_bf16(v.x, v.y); u.y = pack_bf16(v.z, v.w);
      *(uint2*)&sB[r*16 + f4*2] = u;
    }
    __syncthreads();
    short8 a = *(const short8*)&sA[(wave*16 + (lane & 15))*16 + (lane >> 4)*4];
    #pragma unroll
    for (int ni = 0; ni < 8; ni++) {
      short8 b = *(const short8*)&sB[(ni*16 + (lane & 15))*16 + (lane >> 4)*4];
      acc[ni] = __builtin_amdgcn_mfma_f32_16x16x32_bf16(a, b, acc[ni], 0, 0, 0);
    }
  }
  int rbase = wave*16 + (lane >> 4)*4;
  #pragma unroll
  for (int ni = 0; ni < 8; ni++)
    #pragma unroll
    for (int reg = 0; reg < 4; reg++)
      wx[(rowbase + rbase + reg)*NH + ni*16 + (lane & 15)] = acc[ni][reg];
}

// FMA block: one weight group u (rows 2l, 2l+1, 4 k-elems) x 4 node vectors
__device__ __forceinline__ void fma4(uint4 u, const float (*sv)[NH], int d4,
                                     float* o0, float* o1) {
  float w00 = __uint_as_float(u.x << 16), w01 = __uint_as_float(u.x & 0xffff0000u);
  float w02 = __uint_as_float(u.y << 16), w03 = __uint_as_float(u.y & 0xffff0000u);
  float w10 = __uint_as_float(u.z << 16), w11 = __uint_as_float(u.z & 0xffff0000u);
  float w12 = __uint_as_float(u.w << 16), w13 = __uint_as_float(u.w & 0xffff0000u);
  #pragma unroll
  for (int j = 0; j < 4; j++) {
    float4 v = *(const float4*)&sv[j][d4*4];      // wave-uniform: LDS broadcast
    o0[j] += w00*v.x + w01*v.y + w02*v.z + w03*v.w;
    o1[j] += w10*v.x + w11*v.y + w12*v.z + w13*v.w;
  }
}

// Mixed-type variant: per-node weight pointer (duplicate rows hit L1).
__device__ __forceinline__ void matvec4_mixed(const uint2* __restrict__ bwT,
    const int* tj, int lane, const float (*sv)[NH], float* o0, float* o1) {
  const uint2* wt0 = bwT + (size_t)(1 + tj[0])*4096;
  const uint2* wt1 = bwT + (size_t)(1 + tj[1])*4096;
  const uint2* wt2 = bwT + (size_t)(1 + tj[2])*4096;
  const uint2* wt3 = bwT + (size_t)(1 + tj[3])*4096;
  #pragma unroll 4
  for (int d4 = 0; d4 < 32; d4++) {
    int off = d4*128 + 2*lane;
    uint4 u0 = *(const uint4*)&wt0[off];
    uint4 u1 = *(const uint4*)&wt1[off];
    uint4 u2 = *(const uint4*)&wt2[off];
    uint4 u3 = *(const uint4*)&wt3[off];
    const uint4 uu[4] = {u0, u1, u2, u3};
    #pragma unroll
    for (int j = 0; j < 4; j++) {
      float4 v = *(const float4*)&sv[j][d4*4];
      float w00 = __uint_as_float(uu[j].x << 16), w01 = __uint_as_float(uu[j].x & 0xffff0000u);
      float w02 = __uint_as_float(uu[j].y << 16), w03 = __uint_as_float(uu[j].y & 0xffff0000u);
      float w10 = __uint_as_float(uu[j].z << 16), w11 = __uint_as_float(uu[j].z & 0xffff0000u);
      float w12 = __uint_as_float(uu[j].w << 16), w13 = __uint_as_float(uu[j].w & 0xffff0000u);
      o0[j] += w00*v.x + w01*v.y + w02*v.z + w03*v.w;
      o1[j] += w10*v.x + w11*v.y + w12*v.z + w13*v.w;
    }
  }
}

// One block per sentence, 1024 threads = 16 waves. All 13 levels in-block.
// W_hr lives in LDS (every batch uses it -> matvec1 has no global stalls).
// W_rel[t]: first 8 groups preloaded to regs BEFORE matvec1 (latency hidden),
// rest streamed with unroll 8. Level-wide dynamic batch pool over 16 waves.
__global__ __launch_bounds__(1024) void tree_kernel(
    const uint2* __restrict__ bwT, const float* __restrict__ bwh,
    const float* __restrict__ wx, const int* __restrict__ parent,
    const int* __restrict__ dep_type, const int* __restrict__ height,
    float* __restrict__ hbuf) {
  __shared__ float sseg[NT][NH];                  // 64 KB seg accumulators
  __shared__ __align__(16) float sh[16][4][NH];   // 32 KB per-wave batch vectors
  __shared__ __align__(16) uint2 sWhr[4096];      // 32 KB W_hr bf16 (bwT mat 0)
  __shared__ int sord[NT], par_l[NT], typ_l[NT];
  __shared__ int gs[105], fill[104], hist[104];
  int b = blockIdx.x, tid = threadIdx.x;
  int wave = tid >> 6, lane = tid & 63;
  int e0 = 2*lane;
  for (int idx = tid; idx < NT*NH/4; idx += 1024)
    ((float4*)sseg)[idx] = make_float4(0.f,0.f,0.f,0.f);
  for (int idx = tid; idx < 4096; idx += 1024)
    sWhr[idx] = bwT[idx];                         // stage W_hr once per block
  if (tid < 104) hist[tid] = 0;
  __syncthreads();
  int mykey = 0;
  if (tid < NT) {
    int g = b*NT + tid;
    int ty = dep_type[g];
    typ_l[tid] = ty;
    mykey = height[g]*NTYPE + ty;
    par_l[tid] = parent[g];
    atomicAdd(&hist[mykey], 1);                   // LDS atomic
  }
  __syncthreads();
  if (tid == 0) {
    int acc = 0;
    for (int u = 0; u < 104; u++) { gs[u] = acc; acc += hist[u]; }
    gs[104] = acc;
  }
  __syncthreads();
  if (tid < 104) fill[tid] = gs[tid];
  __syncthreads();
  if (tid < NT) {
    int pos = atomicAdd(&fill[mykey], 1);         // LDS atomic
    sord[pos] = tid;
  }
  const float* wxb = wx + (size_t)b*NT*NH;
  float* hb = hbuf + (size_t)b*NT*NH;
  float2 bv = *(const float2*)&bwh[e0];
  __syncthreads();
  for (int k = 0; k < NLEVEL; k++) {
    int ls = gs[k*NTYPE], le = gs[k*NTYPE + NTYPE];
    int nbat = (le - ls + 3) >> 2;
    for (int bi = wave; bi < nbat; bi += 16) {    // dynamic pool over all waves
      int base = ls + bi*4;
      int cnt = le - base; if (cnt > 4) cnt = 4;
      int nl[4], pl[4], tj[4];
      #pragma unroll
      for (int j = 0; j < 4; j++) {
        int it = base + j; if (it >= le) it = le - 1;   // clamp tail
        nl[j] = sord[it];
        pl[j] = par_l[nl[j]];
        tj[j] = typ_l[nl[j]];
      }
      bool pure = (tj[0] == tj[1]) & (tj[1] == tj[2]) & (tj[2] == tj[3]);
      const uint2* wrel_t = bwT + (size_t)(1 + tj[0])*4096;
      // issue W_rel preload FIRST: its L2 latency hides under gathers+matvec1
      uint4 pre[8];
      if (pure) {
        #pragma unroll
        for (int g = 0; g < 8; g++)
          pre[g] = *(const uint4*)&wrel_t[g*128 + 2*lane];
      }
      float2 wxv[4], pw[4], sg[4];
      #pragma unroll
      for (int j = 0; j < 4; j++)
        wxv[j] = *(const float2*)&wxb[(size_t)nl[j]*NH + e0];
      #pragma unroll
      for (int j = 0; j < 4; j++) {
        int p = pl[j] >= 0 ? pl[j] : nl[j];
        pw[j] = *(const float2*)&wxb[(size_t)p*NH + e0];
      }
      #pragma unroll
      for (int j = 0; j < 4; j++)
        sg[j] = *(const float2*)&sseg[nl[j]][e0];
      // finalize h
      #pragma unroll
      for (int j = 0; j < 4; j++) {
        float s0 = ftanh(wxv[j].x + bv.x);
        float s1 = ftanh(wxv[j].y + bv.y);
        float h0, h1;
        if (k == 0) { h0 = s0; h1 = s1; }
        else { h0 = ftanh(sg[j].x + s0); h1 = ftanh(sg[j].y + s1); }
        if (j < cnt)
          *(float2*)&hb[(size_t)nl[j]*NH + e0] = make_float2(h0, h1);  // final h
        *(float2*)&sh[wave][j][e0] = make_float2(h0, h1);  // wave-synchronous LDS
      }
      // matvec1: g = W_hr . h  — weights from LDS, pure issue
      float g0v[4], g1v[4];
      #pragma unroll
      for (int j = 0; j < 4; j++) { g0v[j] = 0.f; g1v[j] = 0.f; }
      #pragma unroll 8
      for (int d4 = 0; d4 < 32; d4++) {
        uint4 u = *(const uint4*)&sWhr[d4*128 + 2*lane];
        fma4(u, sh[wave], d4, g0v, g1v);
      }
      #pragma unroll
      for (int j = 0; j < 4; j++) {               // r = tanh(g + wx_parent)
        float r0 = ftanh(g0v[j] + pw[j].x);
        float r1 = ftanh(g1v[j] + pw[j].y);
        *(float2*)&sh[wave][j][e0] = make_float2(r0, r1);
      }
      // matvec2: infl = W_rel[t] . r
      float o0[4], o1[4];
      #pragma unroll
      for (int j = 0; j < 4; j++) { o0[j] = 0.f; o1[j] = 0.f; }
      if (pure) {
        #pragma unroll
        for (int g = 0; g < 8; g++)
          fma4(pre[g], sh[wave], g, o0, o1);      // preloaded: zero stall
        #pragma unroll 8
        for (int d4 = 8; d4 < 32; d4++) {
          uint4 u = *(const uint4*)&wrel_t[d4*128 + 2*lane];
          fma4(u, sh[wave], d4, o0, o1);
        }
      } else {
        matvec4_mixed(bwT, tj, lane, sh[wave], o0, o1);
      }
      #pragma unroll
      for (int j = 0; j < 4; j++) if (j < cnt && pl[j] >= 0) {
        atomicAdd(&sseg[pl[j]][e0],     o0[j]);   // LDS atomic (in-CU)
        atomicAdd(&sseg[pl[j]][e0 + 1], o1[j]);
      }
    }
    __syncthreads();                              // level boundary (block-local)
  }
}

extern "C" void kernel_launch(void* const* d_in, const int* in_sizes, int n_in,
                              void* d_out, int out_size, void* d_ws, size_t ws_size,
                              hipStream_t stream) {
  const float* token  = (const float*)d_in[0];
  const float* Wwh    = (const float*)d_in[1];
  const float* bwh    = (const float*)d_in[2];
  const float* Whr    = (const float*)d_in[3];
  const float* Wrel   = (const float*)d_in[4];
  const int*   parent = (const int*)d_in[5];
  const int*   dep    = (const int*)d_in[6];
  const int*   height = (const int*)d_in[7];

  float* hbuf = (float*)d_out;                          // final h (write-once)
  float* wx   = (float*)d_ws;                           // [NN,NH] f32, 16MB
  uint2* bwT  = (uint2*)((char*)d_ws + 16777216);       // 288KB bf16 weights

  wcvt_kernel<<<144, 256, 0, stream>>>(Whr, Wrel, bwT);
  wx_kernel<<<NN/64, 256, 0, stream>>>(token, Wwh, wx);
  tree_kernel<<<NB, 1024, 0, stream>>>(bwT, bwh, wx, parent, dep, height, hbuf);
}

// Round 19
// 239.642 us; speedup vs baseline: 1.7696x; 1.1945x over previous
//
#include <hip/hip_runtime.h>
#include <math.h>

#define NB 256
#define NT 128
#define NDW 300
#define NH 128
#define NTYPE 8
#define NLEVEL 13
#define NN (NB*NT)

typedef __attribute__((ext_vector_type(8))) short short8;
typedef __attribute__((ext_vector_type(4))) float f32x4;

__device__ __forceinline__ unsigned int pack_bf16(float a, float b) {
  unsigned int ua = __float_as_uint(a); ua += 0x7fff + ((ua >> 16) & 1);
  unsigned int ub = __float_as_uint(b); ub += 0x7fff + ((ub >> 16) & 1);
  return (ua >> 16) | (ub & 0xffff0000u);
}

// fast tanh: 1 - 2*rcp(e^{2x}+1); exact at +/-inf, ~1e-6 abs error
__device__ __forceinline__ float ftanh(float x) {
  float e = __expf(2.0f * x);
  return 1.0f - 2.0f * __builtin_amdgcn_rcpf(e + 1.0f);
}

// one packed-bf16 dot2: acc += w.lo*v.lo + w.hi*v.hi  (VOP3P, CDNA2+)
__device__ __forceinline__ float dot2a(unsigned int w, unsigned int v, float acc) {
  float r;
  asm("v_dot2_f32_bf16 %0, %1, %2, %3" : "=v"(r) : "v"(w), "v"(v), "v"(acc));
  return r;
}

// Transposed-packed bf16 weights: bwT[mat][d4][row] = uint2 of 4 bf16 =
// W[mat][row][4*d4..4*d4+3]. mat 0 = W_hr, mat 1+t = W_rel[t]. Coalesced build.
__global__ __launch_bounds__(256) void wcvt_kernel(const float* __restrict__ Whr,
    const float* __restrict__ Wrel, uint2* __restrict__ bwT) {
  int flat = blockIdx.x*256 + threadIdx.x;     // 0 .. 9*4096-1
  int mat = flat >> 12, rem = flat & 4095;
  int d4 = rem >> 7, row = rem & 127;
  const float* src = (mat == 0) ? &Whr[row*NH + d4*4]
                                : &Wrel[(size_t)(mat-1)*NH*NH + row*NH + d4*4];
  float4 v = *(const float4*)src;
  uint2 u; u.x = pack_bf16(v.x, v.y); u.y = pack_bf16(v.z, v.w);
  bwT[flat] = u;
}

// wx = token_emb @ W_wh.T via MFMA bf16. Tile 64m x 128n, K chunks of 32 (300 pad 320).
__global__ __launch_bounds__(256) void wx_kernel(const float* __restrict__ x,
    const float* __restrict__ Wwh, float* __restrict__ wx) {
  __shared__ __align__(16) unsigned int sA[64*16];    // [row][16 uints] = 32 bf16/row
  __shared__ __align__(16) unsigned int sB[128*16];
  int tid = threadIdx.x;
  int wave = tid >> 6, lane = tid & 63;
  size_t rowbase = (size_t)blockIdx.x * 64;
  f32x4 acc[8];
  #pragma unroll
  for (int ni = 0; ni < 8; ni++) acc[ni] = (f32x4){0.f,0.f,0.f,0.f};
  for (int kc = 0; kc < 320; kc += 32) {
    __syncthreads();
    #pragma unroll
    for (int q = 0; q < 2; q++) {             // stage A: 64 rows x 8 float4
      int flat = tid + q*256; int r = flat >> 3, f4 = flat & 7;
      int k0 = kc + f4*4;
      float4 v = make_float4(0.f,0.f,0.f,0.f);
      if (k0 + 3 < NDW) v = *(const float4*)&x[(rowbase + r)*NDW + k0];
      uint2 u; u.x = pack_bf16(v.x, v.y); u.y = pack_bf16(v.z, v.w);
      *(uint2*)&sA[r*16 + f4*2] = u;
    }
    #pragma unroll
    for (int q = 0; q < 4; q++) {             // stage B: 128 rows x 8 float4
      int flat = tid + q*256; int r = flat >> 3, f4 = flat & 7;
      int k0 = kc + f4*4;
      float4 v = make_float4(0.f,0.f,0.f,0.f);
      if (k0 + 3 < NDW) v = *(const float4*)&Wwh[(size_t)r*NDW + k0];
      uint2 u; u.x = pack_bf16(v.x, v.y); u.y = pack_bf16(v.z, v.w);
      *(uint2*)&sB[r*16 + f4*2] = u;
    }
    __syncthreads();
    short8 a = *(const short8*)&sA[(wave*16 + (lane & 15))*16 + (lane >> 4)*4];
    #pragma unroll
    for (int ni = 0; ni < 8; ni++) {
      short8 b = *(const short8*)&sB[(ni*16 + (lane & 15))*16 + (lane >> 4)*4];
      acc[ni] = __builtin_amdgcn_mfma_f32_16x16x32_bf16(a, b, acc[ni], 0, 0, 0);
    }
  }
  int rbase = wave*16 + (lane >> 4)*4;
  #pragma unroll
  for (int ni = 0; ni < 8; ni++)
    #pragma unroll
    for (int reg = 0; reg < 4; reg++)
      wx[(rowbase + rbase + reg)*NH + ni*16 + (lane & 15)] = acc[ni][reg];
}

// 4-node batched matvec, dot2 pipe. Weight stream wt (LDS or global, same code):
// lane owns output rows 2l, 2l+1; vectors are packed-bf16 panels (broadcast reads).
__device__ __forceinline__ void matvec4_d2(const uint2* __restrict__ wt,
    int lane, const unsigned int (*sv)[64], float* o0, float* o1) {
  #pragma unroll
  for (int j = 0; j < 4; j++) { o0[j] = 0.f; o1[j] = 0.f; }
  #pragma unroll 8
  for (int d4 = 0; d4 < 32; d4++) {
    uint4 u = *(const uint4*)&wt[d4*128 + 2*lane];   // rows 2l (x,y), 2l+1 (z,w)
    #pragma unroll
    for (int j = 0; j < 4; j++) {
      uint2 vv = *(const uint2*)&sv[j][d4*2];        // wave-uniform broadcast
      o0[j] = dot2a(u.x, vv.x, o0[j]);
      o0[j] = dot2a(u.y, vv.y, o0[j]);
      o1[j] = dot2a(u.z, vv.x, o1[j]);
      o1[j] = dot2a(u.w, vv.y, o1[j]);
    }
  }
}

// Mixed-type variant: per-node weight pointers (duplicate rows hit L1).
__device__ __forceinline__ void matvec4_d2mixed(const uint2* __restrict__ bwT,
    const int* tj, int lane, const unsigned int (*sv)[64], float* o0, float* o1) {
  const uint2* wt0 = bwT + (size_t)(1 + tj[0])*4096;
  const uint2* wt1 = bwT + (size_t)(1 + tj[1])*4096;
  const uint2* wt2 = bwT + (size_t)(1 + tj[2])*4096;
  const uint2* wt3 = bwT + (size_t)(1 + tj[3])*4096;
  #pragma unroll
  for (int j = 0; j < 4; j++) { o0[j] = 0.f; o1[j] = 0.f; }
  #pragma unroll 4
  for (int d4 = 0; d4 < 32; d4++) {
    int off = d4*128 + 2*lane;
    uint4 uu[4];
    uu[0] = *(const uint4*)&wt0[off];
    uu[1] = *(const uint4*)&wt1[off];
    uu[2] = *(const uint4*)&wt2[off];
    uu[3] = *(const uint4*)&wt3[off];
    #pragma unroll
    for (int j = 0; j < 4; j++) {
      uint2 vv = *(const uint2*)&sv[j][d4*2];
      o0[j] = dot2a(uu[j].x, vv.x, o0[j]);
      o0[j] = dot2a(uu[j].y, vv.y, o0[j]);
      o1[j] = dot2a(uu[j].z, vv.x, o1[j]);
      o1[j] = dot2a(uu[j].w, vv.y, o1[j]);
    }
  }
}

// One block per sentence, 1024 threads = 16 waves. All 13 levels in-block.
// W_hr in LDS; batch vectors as packed-bf16 LDS panels; dot2 matvecs;
// level-wide dynamic batch pool over 16 waves; seg accumulates in LDS.
__global__ __launch_bounds__(1024) void tree_kernel(
    const uint2* __restrict__ bwT, const float* __restrict__ bwh,
    const float* __restrict__ wx, const int* __restrict__ parent,
    const int* __restrict__ dep_type, const int* __restrict__ height,
    float* __restrict__ hbuf) {
  __shared__ float sseg[NT][NH];                  // 64 KB seg accumulators
  __shared__ __align__(16) unsigned int ssh[16][4][64]; // 16 KB bf16 panels
  __shared__ __align__(16) uint2 sWhr[4096];      // 32 KB W_hr bf16
  __shared__ int sord[NT], par_l[NT], typ_l[NT];
  __shared__ int gs[105], fill[104], hist[104];
  int b = blockIdx.x, tid = threadIdx.x;
  int wave = tid >> 6, lane = tid & 63;
  int e0 = 2*lane;
  for (int idx = tid; idx < NT*NH/4; idx += 1024)
    ((float4*)sseg)[idx] = make_float4(0.f,0.f,0.f,0.f);
  for (int idx = tid; idx < 4096; idx += 1024)
    sWhr[idx] = bwT[idx];                         // stage W_hr once per block
  if (tid < 104) hist[tid] = 0;
  __syncthreads();
  int mykey = 0;
  if (tid < NT) {
    int g = b*NT + tid;
    int ty = dep_type[g];
    typ_l[tid] = ty;
    mykey = height[g]*NTYPE + ty;
    par_l[tid] = parent[g];
    atomicAdd(&hist[mykey], 1);                   // LDS atomic
  }
  __syncthreads();
  if (tid == 0) {
    int acc = 0;
    for (int u = 0; u < 104; u++) { gs[u] = acc; acc += hist[u]; }
    gs[104] = acc;
  }
  __syncthreads();
  if (tid < 104) fill[tid] = gs[tid];
  __syncthreads();
  if (tid < NT) {
    int pos = atomicAdd(&fill[mykey], 1);         // LDS atomic
    sord[pos] = tid;
  }
  const float* wxb = wx + (size_t)b*NT*NH;
  float* hb = hbuf + (size_t)b*NT*NH;
  float2 bv = *(const float2*)&bwh[e0];
  __syncthreads();
  for (int k = 0; k < NLEVEL; k++) {
    int ls = gs[k*NTYPE], le = gs[k*NTYPE + NTYPE];
    int nbat = (le - ls + 3) >> 2;
    for (int bi = wave; bi < nbat; bi += 16) {    // dynamic pool over all waves
      int base = ls + bi*4;
      int cnt = le - base; if (cnt > 4) cnt = 4;
      int nl[4], pl[4], tj[4];
      #pragma unroll
      for (int j = 0; j < 4; j++) {
        int it = base + j; if (it >= le) it = le - 1;   // clamp tail
        nl[j] = sord[it];
        pl[j] = par_l[nl[j]];
        tj[j] = typ_l[nl[j]];
      }
      float2 wxv[4], pw[4], sg[4];
      #pragma unroll
      for (int j = 0; j < 4; j++)
        wxv[j] = *(const float2*)&wxb[(size_t)nl[j]*NH + e0];
      #pragma unroll
      for (int j = 0; j < 4; j++) {
        int p = pl[j] >= 0 ? pl[j] : nl[j];
        pw[j] = *(const float2*)&wxb[(size_t)p*NH + e0];
      }
      #pragma unroll
      for (int j = 0; j < 4; j++)
        sg[j] = *(const float2*)&sseg[nl[j]][e0];
      // finalize h -> global (fp32) + bf16 panel
      #pragma unroll
      for (int j = 0; j < 4; j++) {
        float s0 = ftanh(wxv[j].x + bv.x);
        float s1 = ftanh(wxv[j].y + bv.y);
        float h0, h1;
        if (k == 0) { h0 = s0; h1 = s1; }
        else { h0 = ftanh(sg[j].x + s0); h1 = ftanh(sg[j].y + s1); }
        if (j < cnt)
          *(float2*)&hb[(size_t)nl[j]*NH + e0] = make_float2(h0, h1);  // final h
        ssh[wave][j][lane] = pack_bf16(h0, h1);   // wave-synchronous LDS
      }
      // matvec1: g = W_hr . h  (LDS weights, dot2 pipe)
      float g0v[4], g1v[4];
      matvec4_d2(sWhr, lane, ssh[wave], g0v, g1v);
      #pragma unroll
      for (int j = 0; j < 4; j++) {               // r = tanh(g + wx_parent)
        float r0 = ftanh(g0v[j] + pw[j].x);
        float r1 = ftanh(g1v[j] + pw[j].y);
        ssh[wave][j][lane] = pack_bf16(r0, r1);
      }
      // matvec2: infl = W_rel[t] . r
      float o0[4], o1[4];
      bool pure = (tj[0] == tj[1]) & (tj[1] == tj[2]) & (tj[2] == tj[3]);
      if (pure)
        matvec4_d2(bwT + (size_t)(1 + tj[0])*4096, lane, ssh[wave], o0, o1);
      else
        matvec4_d2mixed(bwT, tj, lane, ssh[wave], o0, o1);
      #pragma unroll
      for (int j = 0; j < 4; j++) if (j < cnt && pl[j] >= 0) {
        atomicAdd(&sseg[pl[j]][e0],     o0[j]);   // LDS atomic (in-CU)
        atomicAdd(&sseg[pl[j]][e0 + 1], o1[j]);
      }
    }
    __syncthreads();                              // level boundary (block-local)
  }
}

extern "C" void kernel_launch(void* const* d_in, const int* in_sizes, int n_in,
                              void* d_out, int out_size, void* d_ws, size_t ws_size,
                              hipStream_t stream) {
  const float* token  = (const float*)d_in[0];
  const float* Wwh    = (const float*)d_in[1];
  const float* bwh    = (const float*)d_in[2];
  const float* Whr    = (const float*)d_in[3];
  const float* Wrel   = (const float*)d_in[4];
  const int*   parent = (const int*)d_in[5];
  const int*   dep    = (const int*)d_in[6];
  const int*   height = (const int*)d_in[7];

  float* hbuf = (float*)d_out;                          // final h (write-once)
  float* wx   = (float*)d_ws;                           // [NN,NH] f32, 16MB
  uint2* bwT  = (uint2*)((char*)d_ws + 16777216);       // 288KB bf16 weights

  wcvt_kernel<<<144, 256, 0, stream>>>(Whr, Wrel, bwT);
  wx_kernel<<<NN/64, 256, 0, stream>>>(token, Wwh, wx);
  tree_kernel<<<NB, 1024, 0, stream>>>(bwT, bwh, wx, parent, dep, height, hbuf);
}